// Round 10
// baseline (44.022 us; speedup 1.0000x reference)
//
#include <hip/hip_runtime.h>

#define BB 2
#define SDIM 1024
#define DDIM 128
#define K1_ROWS 2

#define F4GET(v,k) ((k)==0?(v).x:((k)==1?(v).y:((k)==2?(v).z:(v).w)))

typedef _Float16 h2v __attribute__((ext_vector_type(2)));
typedef _Float16 h8v __attribute__((ext_vector_type(8)));

__device__ __forceinline__ h2v habs2(h2v t) {
    unsigned u = __builtin_bit_cast(unsigned, t) & 0x7FFF7FFFu;
    return __builtin_bit_cast(h2v, u);
}

__device__ __forceinline__ float hdot2(h2v a, h2v b, float acc) {
#if __has_builtin(__builtin_amdgcn_fdot2)
    return __builtin_amdgcn_fdot2(a, b, acc, false);
#else
    acc = fmaf((float)a.x, (float)b.x, acc);
    return fmaf((float)a.y, (float)b.y, acc);
#endif
}

__device__ __forceinline__ h2v hfma2(h2v a, h2v b, h2v c) {
#if __has_builtin(__builtin_elementwise_fma)
    return __builtin_elementwise_fma(a, b, c);
#else
    return a * b + c;   // v_pk_mul_f16 + v_pk_add_f16
#endif
}

// Row swizzle (R8): rows 8/16 apart land on different bank-quads.
__device__ __forceinline__ int rswz(int row) {
    return (row & 7) ^ ((row >> 3) & 7);
}

// ---------------- Kernel 1: projections + row dot products ----------------
__global__ __launch_bounds__(256) void proj_kernel(
    const float* __restrict__ x, const float* __restrict__ W1,
    const float* __restrict__ b1, const float* __restrict__ W2,
    const float* __restrict__ b2,
    ushort* __restrict__ hi16, ushort* __restrict__ hjb16,
    float* __restrict__ si2, float* __restrict__ sj2)
{
    __shared__ float sX[K1_ROWS][DDIM];
    __shared__ float sRed[4][K1_ROWS];
    const int tid  = threadIdx.x;
    const int d    = tid & 127;
    const int half = tid >> 7;
    const int r0   = blockIdx.x * K1_ROWS;

    if (tid < K1_ROWS * DDIM / 4) {
        reinterpret_cast<float4*>(&sX[0][0])[tid] =
            reinterpret_cast<const float4*>(x + (size_t)r0 * DDIM)[tid];
    }
    __syncthreads();

    const float* Wh = W1 + (size_t)half * DDIM * DDIM;

    float acc[K1_ROWS];
    #pragma unroll
    for (int r = 0; r < K1_ROWS; ++r) acc[r] = 0.f;

    #pragma unroll 4
    for (int k = 0; k < DDIM; k += 4) {
        float4 xv[K1_ROWS];
        #pragma unroll
        for (int r = 0; r < K1_ROWS; ++r)
            xv[r] = *reinterpret_cast<const float4*>(&sX[r][k]);
        #pragma unroll
        for (int kk = 0; kk < 4; ++kk) {
            float w = Wh[(size_t)(k + kk) * DDIM + d];
            #pragma unroll
            for (int r = 0; r < K1_ROWS; ++r)
                acc[r] = fmaf(F4GET(xv[r], kk), w, acc[r]);
        }
    }

    if (half) {
        const float bv = b1[d];
        #pragma unroll
        for (int r = 0; r < K1_ROWS; ++r) acc[r] += bv;
    }

    ushort* hout = half ? hjb16 : hi16;
    #pragma unroll
    for (int r = 0; r < K1_ROWS; ++r) {
        _Float16 hv = (_Float16)acc[r];
        hout[(size_t)(r0 + r) * DDIM + d] = __builtin_bit_cast(ushort, hv);
    }

    const float wv = W2[d];
    const int lane = tid & 63;
    const int wave = tid >> 6;
    #pragma unroll
    for (int r = 0; r < K1_ROWS; ++r) {
        float v = acc[r] * wv;
        #pragma unroll
        for (int off = 32; off >= 1; off >>= 1)
            v += __shfl_xor(v, off, 64);
        if (lane == 0) sRed[wave][r] = v;
    }
    __syncthreads();
    if (tid < K1_ROWS) {
        si2[r0 + tid] = 0.5f * (sRed[0][tid] + sRed[1][tid]);
    } else if (tid < 2 * K1_ROWS) {
        int r = tid - K1_ROWS;
        sj2[r0 + r] = 0.5f * (sRed[2][r] + sRed[3][r]) + b2[0];
    }
}

// ---------------- edgeA: R8-exact (dot2 path, d-split, 512 thr) -----------
__global__ __launch_bounds__(512) void edge_kernel_a(
    const ushort* __restrict__ hi16, const ushort* __restrict__ hjb16,
    const float* __restrict__ si2, const float* __restrict__ sj2,
    const float* __restrict__ W2, float* __restrict__ out)
{
    __shared__ float4 sTileI[1024];
    __shared__ float4 sTileJ[1024];
    __shared__ float4 sWf[16];
    __shared__ float  sSi[64];
    __shared__ float  sSj[64];

    const int b   = blockIdx.z;
    const int i0  = blockIdx.y * 64;
    const int j0  = blockIdx.x * 64;
    const int tid = threadIdx.x;

    {
        const h8v* srcI = reinterpret_cast<const h8v*>(hi16  + ((size_t)b * SDIM + i0) * DDIM);
        const h8v* srcJ = reinterpret_cast<const h8v*>(hjb16 + ((size_t)b * SDIM + j0) * DDIM);
        h8v* dI = reinterpret_cast<h8v*>(sTileI);
        h8v* dJ = reinterpret_cast<h8v*>(sTileJ);
        #pragma unroll
        for (int p = 0; p < 2; ++p) {
            int idx = p * 512 + tid;
            int row = idx >> 4, ch = idx & 15;
            int cs  = ch ^ rswz(row);
            dI[row * 16 + cs] = srcI[idx];
            dJ[row * 16 + cs] = srcJ[idx];
        }
    }
    if (tid < DDIM) {
        _Float16 wv = (_Float16)(0.5f * W2[tid]);
        reinterpret_cast<ushort*>(sWf)[tid] = __builtin_bit_cast(ushort, wv);
    } else if (tid < DDIM + 64) {
        sSi[tid - DDIM] = si2[b * SDIM + i0 + (tid - DDIM)];
    } else if (tid < DDIM + 128) {
        sSj[tid - DDIM - 64] = sj2[b * SDIM + j0 + (tid - DDIM - 64)];
    }
    __syncthreads();

    const int t8 = tid & 255;
    const int g  = tid >> 8;
    const int tx = t8 & 15;
    const int ty = t8 >> 4;
    const int ri = ty * 4;
    const int cj = tx * 4;

    int swzA[4], swzB[4];
    #pragma unroll
    for (int r = 0; r < 4; ++r) swzA[r] = rswz(ri + r);
    #pragma unroll
    for (int c = 0; c < 4; ++c) swzB[c] = rswz(cj + c);

    float acc[4][4];
    #pragma unroll
    for (int r = 0; r < 4; ++r)
        #pragma unroll
        for (int c = 0; c < 4; ++c) acc[r][c] = 0.f;

    const h8v* sAi = reinterpret_cast<const h8v*>(sTileI);
    const h8v* sBj = reinterpret_cast<const h8v*>(sTileJ);
    const h8v* sWv = reinterpret_cast<const h8v*>(sWf);

    const int ch0 = g * 8;
    #pragma unroll 2
    for (int ch = ch0; ch < ch0 + 8; ++ch) {
        h8v A[4], Bv[4];
        #pragma unroll
        for (int r = 0; r < 4; ++r)
            A[r] = sAi[(ri + r) * 16 + (ch ^ swzA[r])];
        #pragma unroll
        for (int c = 0; c < 4; ++c)
            Bv[c] = sBj[(cj + c) * 16 + (ch ^ swzB[c])];
        const h8v Wv = sWv[ch];

        #pragma unroll
        for (int r = 0; r < 4; ++r) {
            const h2v* ap = reinterpret_cast<const h2v*>(&A[r]);
            #pragma unroll
            for (int c = 0; c < 4; ++c) {
                const h2v* bp = reinterpret_cast<const h2v*>(&Bv[c]);
                const h2v* wp = reinterpret_cast<const h2v*>(&Wv);
                float a = acc[r][c];
                #pragma unroll
                for (int k = 0; k < 4; ++k) {
                    h2v t = ap[k] + bp[k];
                    a = hdot2(habs2(t), wp[k], a);
                }
                acc[r][c] = a;
            }
        }
    }

    __syncthreads();
    if (g == 1) {
        #pragma unroll
        for (int r = 0; r < 4; ++r)
            sTileI[t8 * 4 + (r ^ (t8 & 3))] =
                make_float4(acc[r][0], acc[r][1], acc[r][2], acc[r][3]);
    }
    __syncthreads();
    if (g == 0) {
        #pragma unroll
        for (int r = 0; r < 4; ++r) {
            const float4 p = sTileI[t8 * 4 + (r ^ (t8 & 3))];
            const float sv = sSi[ri + r];
            float4 o;
            o.x = acc[r][0] + p.x + sv + sSj[cj + 0];
            o.y = acc[r][1] + p.y + sv + sSj[cj + 1];
            o.z = acc[r][2] + p.z + sv + sSj[cj + 2];
            o.w = acc[r][3] + p.w + sv + sSj[cj + 3];
            size_t base = (size_t)b * SDIM * SDIM
                        + (size_t)(i0 + ri + r) * SDIM + j0 + cj;
            *reinterpret_cast<float4*>(out + base) = o;
        }
    }
}

// ---------------- edgeB: identical structure, v_pk_fma_f16 path -----------
// Same LDS layout/instr count as R7-edge; dot2 replaced by pk_fma with split
// f16x2 accumulators (accP: kgroups 0-1, accQ: kgroups 2-3; 32 terms each).
__global__ __launch_bounds__(256) void edge_kernel_b(
    const ushort* __restrict__ hi16, const ushort* __restrict__ hjb16,
    const float* __restrict__ si2, const float* __restrict__ sj2,
    const float* __restrict__ W2, float* __restrict__ out)
{
    __shared__ ushort sHi[64 * DDIM];
    __shared__ ushort sHj[64 * DDIM];
    __shared__ ushort sWh[DDIM];
    __shared__ float  sSi[64];
    __shared__ float  sSj[64];

    const int b   = blockIdx.z;
    const int i0  = blockIdx.y * 64;
    const int j0  = blockIdx.x * 64;
    const int tid = threadIdx.x;

    {
        const h8v* srcI = reinterpret_cast<const h8v*>(hi16  + ((size_t)b * SDIM + i0) * DDIM);
        const h8v* srcJ = reinterpret_cast<const h8v*>(hjb16 + ((size_t)b * SDIM + j0) * DDIM);
        h8v* dI = reinterpret_cast<h8v*>(sHi);
        h8v* dJ = reinterpret_cast<h8v*>(sHj);
        #pragma unroll
        for (int p = 0; p < 4; ++p) {
            int idx = p * 256 + tid;
            int row = idx >> 4, ch = idx & 15;
            int cs  = ch ^ rswz(row);
            dI[row * 16 + cs] = srcI[idx];
            dJ[row * 16 + cs] = srcJ[idx];
        }
    }
    if (tid < DDIM) {
        _Float16 wv = (_Float16)(0.5f * W2[tid]);
        sWh[tid] = __builtin_bit_cast(ushort, wv);
    } else if (tid < DDIM + 64) {
        sSi[tid - DDIM] = si2[b * SDIM + i0 + (tid - DDIM)];
    } else {
        sSj[tid - DDIM - 64] = sj2[b * SDIM + j0 + (tid - DDIM - 64)];
    }
    __syncthreads();

    const int tx = tid & 15;
    const int ty = tid >> 4;
    const int ri = ty * 4;
    const int cj = tx * 4;

    int swzA[4], swzB[4];
    #pragma unroll
    for (int r = 0; r < 4; ++r) swzA[r] = rswz(ri + r);
    #pragma unroll
    for (int c = 0; c < 4; ++c) swzB[c] = rswz(cj + c);

    h2v accP[4][4], accQ[4][4];
    #pragma unroll
    for (int r = 0; r < 4; ++r)
        #pragma unroll
        for (int c = 0; c < 4; ++c) {
            accP[r][c] = (h2v)(_Float16)0;
            accQ[r][c] = (h2v)(_Float16)0;
        }

    const h8v* sAi = reinterpret_cast<const h8v*>(sHi);
    const h8v* sBj = reinterpret_cast<const h8v*>(sHj);
    const h8v* sWv = reinterpret_cast<const h8v*>(sWh);

    #pragma unroll 2
    for (int ch = 0; ch < 16; ++ch) {
        h8v A[4], Bv[4];
        #pragma unroll
        for (int r = 0; r < 4; ++r)
            A[r] = sAi[(ri + r) * 16 + (ch ^ swzA[r])];
        #pragma unroll
        for (int c = 0; c < 4; ++c)
            Bv[c] = sBj[(cj + c) * 16 + (ch ^ swzB[c])];
        const h8v Wv = sWv[ch];
        const h2v* wp = reinterpret_cast<const h2v*>(&Wv);

        #pragma unroll
        for (int r = 0; r < 4; ++r) {
            const h2v* ap = reinterpret_cast<const h2v*>(&A[r]);
            #pragma unroll
            for (int c = 0; c < 4; ++c) {
                const h2v* bp = reinterpret_cast<const h2v*>(&Bv[c]);
                h2v t0 = ap[0] + bp[0];            // v_pk_add_f16
                h2v t1 = ap[1] + bp[1];
                h2v t2 = ap[2] + bp[2];
                h2v t3 = ap[3] + bp[3];
                accP[r][c] = hfma2(habs2(t0), wp[0], accP[r][c]);  // v_pk_fma_f16
                accP[r][c] = hfma2(habs2(t1), wp[1], accP[r][c]);
                accQ[r][c] = hfma2(habs2(t2), wp[2], accQ[r][c]);
                accQ[r][c] = hfma2(habs2(t3), wp[3], accQ[r][c]);
            }
        }
    }

    #pragma unroll
    for (int r = 0; r < 4; ++r) {
        const float sv = sSi[ri + r];
        float4 o;
        o.x = ((float)accP[r][0].x + (float)accP[r][0].y)
            + ((float)accQ[r][0].x + (float)accQ[r][0].y) + sv + sSj[cj + 0];
        o.y = ((float)accP[r][1].x + (float)accP[r][1].y)
            + ((float)accQ[r][1].x + (float)accQ[r][1].y) + sv + sSj[cj + 1];
        o.z = ((float)accP[r][2].x + (float)accP[r][2].y)
            + ((float)accQ[r][2].x + (float)accQ[r][2].y) + sv + sSj[cj + 2];
        o.w = ((float)accP[r][3].x + (float)accP[r][3].y)
            + ((float)accQ[r][3].x + (float)accQ[r][3].y) + sv + sSj[cj + 3];
        size_t base = (size_t)b * SDIM * SDIM + (size_t)(i0 + ri + r) * SDIM + j0 + cj;
        *reinterpret_cast<float4*>(out + base) = o;
    }
}

extern "C" void kernel_launch(void* const* d_in, const int* in_sizes, int n_in,
                              void* d_out, int out_size, void* d_ws, size_t ws_size,
                              hipStream_t stream) {
    const float* x  = (const float*)d_in[0];
    const float* W1 = (const float*)d_in[1];
    const float* b1 = (const float*)d_in[2];
    const float* W2 = (const float*)d_in[3];
    const float* b2 = (const float*)d_in[4];
    float* out = (float*)d_out;

    char* ws = (char*)d_ws;
    ushort* hi16  = (ushort*)ws;                                   // B*S*D f16
    ushort* hjb16 = hi16 + (size_t)BB * SDIM * DDIM;               // B*S*D f16
    float*  si2   = (float*)(hjb16 + (size_t)BB * SDIM * DDIM);    // B*S f32
    float*  sj2   = si2 + (size_t)BB * SDIM;                       // B*S f32

    proj_kernel<<<BB * SDIM / K1_ROWS, 256, 0, stream>>>(x, W1, b1, W2, b2, hi16, hjb16, si2, sj2);
    // A/B attribution probe: edgeA (R8-exact, dot2) then edgeB (pk_fma_f16).
    // Both write the full output; edgeB lands last and is validated.
    edge_kernel_a<<<dim3(SDIM / 64, SDIM / 64, BB), 512, 0, stream>>>(hi16, hjb16, si2, sj2, W2, out);
    edge_kernel_b<<<dim3(SDIM / 64, SDIM / 64, BB), 256, 0, stream>>>(hi16, hjb16, si2, sj2, W2, out);
}

// Round 11
// 28.907 us; speedup vs baseline: 1.5229x; 1.5229x over previous
//
#include <hip/hip_runtime.h>

#define BB 2
#define SDIM 1024
#define DDIM 128
#define K1_ROWS 2

#define F4GET(v,k) ((k)==0?(v).x:((k)==1?(v).y:((k)==2?(v).z:(v).w)))

typedef _Float16 h2v __attribute__((ext_vector_type(2)));
typedef _Float16 h8v __attribute__((ext_vector_type(8)));

__device__ __forceinline__ h2v habs2(h2v t) {
    unsigned u = __builtin_bit_cast(unsigned, t) & 0x7FFF7FFFu;
    return __builtin_bit_cast(h2v, u);
}

__device__ __forceinline__ h2v hfma2(h2v a, h2v b, h2v c) {
#if __has_builtin(__builtin_elementwise_fma)
    return __builtin_elementwise_fma(a, b, c);   // v_pk_fma_f16
#else
    return a * b + c;
#endif
}

// Row swizzle: rows 8/16 apart land on different bank-quads.
__device__ __forceinline__ int rswz(int row) {
    return (row & 7) ^ ((row >> 3) & 7);
}

// ---------------- Kernel 1: projections + row dot products ----------------
// (unchanged from R10)
__global__ __launch_bounds__(256) void proj_kernel(
    const float* __restrict__ x, const float* __restrict__ W1,
    const float* __restrict__ b1, const float* __restrict__ W2,
    const float* __restrict__ b2,
    ushort* __restrict__ hi16, ushort* __restrict__ hjb16,
    float* __restrict__ si2, float* __restrict__ sj2)
{
    __shared__ float sX[K1_ROWS][DDIM];
    __shared__ float sRed[4][K1_ROWS];
    const int tid  = threadIdx.x;
    const int d    = tid & 127;
    const int half = tid >> 7;
    const int r0   = blockIdx.x * K1_ROWS;

    if (tid < K1_ROWS * DDIM / 4) {
        reinterpret_cast<float4*>(&sX[0][0])[tid] =
            reinterpret_cast<const float4*>(x + (size_t)r0 * DDIM)[tid];
    }
    __syncthreads();

    const float* Wh = W1 + (size_t)half * DDIM * DDIM;

    float acc[K1_ROWS];
    #pragma unroll
    for (int r = 0; r < K1_ROWS; ++r) acc[r] = 0.f;

    #pragma unroll 4
    for (int k = 0; k < DDIM; k += 4) {
        float4 xv[K1_ROWS];
        #pragma unroll
        for (int r = 0; r < K1_ROWS; ++r)
            xv[r] = *reinterpret_cast<const float4*>(&sX[r][k]);
        #pragma unroll
        for (int kk = 0; kk < 4; ++kk) {
            float w = Wh[(size_t)(k + kk) * DDIM + d];
            #pragma unroll
            for (int r = 0; r < K1_ROWS; ++r)
                acc[r] = fmaf(F4GET(xv[r], kk), w, acc[r]);
        }
    }

    if (half) {
        const float bv = b1[d];
        #pragma unroll
        for (int r = 0; r < K1_ROWS; ++r) acc[r] += bv;
    }

    ushort* hout = half ? hjb16 : hi16;
    #pragma unroll
    for (int r = 0; r < K1_ROWS; ++r) {
        _Float16 hv = (_Float16)acc[r];
        hout[(size_t)(r0 + r) * DDIM + d] = __builtin_bit_cast(ushort, hv);
    }

    const float wv = W2[d];
    const int lane = tid & 63;
    const int wave = tid >> 6;
    #pragma unroll
    for (int r = 0; r < K1_ROWS; ++r) {
        float v = acc[r] * wv;
        #pragma unroll
        for (int off = 32; off >= 1; off >>= 1)
            v += __shfl_xor(v, off, 64);
        if (lane == 0) sRed[wave][r] = v;
    }
    __syncthreads();
    if (tid < K1_ROWS) {
        si2[r0 + tid] = 0.5f * (sRed[0][tid] + sRed[1][tid]);
    } else if (tid < 2 * K1_ROWS) {
        int r = tid - K1_ROWS;
        sj2[r0 + r] = 0.5f * (sRed[2][r] + sRed[3][r]) + b2[0];
    }
}

// ---------------- Kernel 2: pairwise edge logits ----------------
// out[b,i,j] = si2[b,i] + sj2[b,j] + sum_d |hi[b,i,d]+hjb[b,j,d]| * 0.5*w2[d]
// R10-edgeB inner loop (v_pk_fma_f16 — dot2 is slow on gfx950, R10 A/B probe)
// + R8 d-split: 512 thr, wave-group g = tid>>8 does d-chunks [8g, 8g+8);
// partials combined through the dead A-tile LDS. 4 waves/SIMD for latency
// hiding at unchanged per-CU LDS instruction traffic.
__global__ __launch_bounds__(512) void edge_kernel(
    const ushort* __restrict__ hi16, const ushort* __restrict__ hjb16,
    const float* __restrict__ si2, const float* __restrict__ sj2,
    const float* __restrict__ W2, float* __restrict__ out)
{
    __shared__ float4 sTileI[1024];   // 16 KB  A tile (h8v slots) / combine buf
    __shared__ float4 sTileJ[1024];   // 16 KB  B tile
    __shared__ float4 sWf[16];        // 0.5*w2 as f16
    __shared__ float  sSi[64];
    __shared__ float  sSj[64];

    const int b   = blockIdx.z;
    const int i0  = blockIdx.y * 64;
    const int j0  = blockIdx.x * 64;
    const int tid = threadIdx.x;

    {
        const h8v* srcI = reinterpret_cast<const h8v*>(hi16  + ((size_t)b * SDIM + i0) * DDIM);
        const h8v* srcJ = reinterpret_cast<const h8v*>(hjb16 + ((size_t)b * SDIM + j0) * DDIM);
        h8v* dI = reinterpret_cast<h8v*>(sTileI);
        h8v* dJ = reinterpret_cast<h8v*>(sTileJ);
        #pragma unroll
        for (int p = 0; p < 2; ++p) {
            int idx = p * 512 + tid;          // 0..1023
            int row = idx >> 4, ch = idx & 15;
            int cs  = ch ^ rswz(row);
            dI[row * 16 + cs] = srcI[idx];
            dJ[row * 16 + cs] = srcJ[idx];
        }
    }
    if (tid < DDIM) {
        _Float16 wv = (_Float16)(0.5f * W2[tid]);
        reinterpret_cast<ushort*>(sWf)[tid] = __builtin_bit_cast(ushort, wv);
    } else if (tid < DDIM + 64) {
        sSi[tid - DDIM] = si2[b * SDIM + i0 + (tid - DDIM)];
    } else if (tid < DDIM + 128) {
        sSj[tid - DDIM - 64] = sj2[b * SDIM + j0 + (tid - DDIM - 64)];
    }
    __syncthreads();

    const int t8 = tid & 255;
    const int g  = tid >> 8;       // d-half: chunks [8g, 8g+8)
    const int tx = t8 & 15;        // j: cols tx*4 .. +3
    const int ty = t8 >> 4;        // i: rows ty*4 .. +3
    const int ri = ty * 4;
    const int cj = tx * 4;

    int swzA[4], swzB[4];
    #pragma unroll
    for (int r = 0; r < 4; ++r) swzA[r] = rswz(ri + r);
    #pragma unroll
    for (int c = 0; c < 4; ++c) swzB[c] = rswz(cj + c);

    // Split f16x2 accumulators: accP = kgroups 0-1, accQ = kgroups 2-3
    // (each sums 16 of the 32 per-half terms -> f16 rounding stays small).
    h2v accP[4][4], accQ[4][4];
    #pragma unroll
    for (int r = 0; r < 4; ++r)
        #pragma unroll
        for (int c = 0; c < 4; ++c) {
            accP[r][c] = (h2v)(_Float16)0;
            accQ[r][c] = (h2v)(_Float16)0;
        }

    const h8v* sAi = reinterpret_cast<const h8v*>(sTileI);
    const h8v* sBj = reinterpret_cast<const h8v*>(sTileJ);
    const h8v* sWv = reinterpret_cast<const h8v*>(sWf);

    const int ch0 = g * 8;
    #pragma unroll 2
    for (int ch = ch0; ch < ch0 + 8; ++ch) {
        h8v A[4], Bv[4];
        #pragma unroll
        for (int r = 0; r < 4; ++r)
            A[r] = sAi[(ri + r) * 16 + (ch ^ swzA[r])];
        #pragma unroll
        for (int c = 0; c < 4; ++c)
            Bv[c] = sBj[(cj + c) * 16 + (ch ^ swzB[c])];
        const h8v Wv = sWv[ch];
        const h2v* wp = reinterpret_cast<const h2v*>(&Wv);

        #pragma unroll
        for (int r = 0; r < 4; ++r) {
            const h2v* ap = reinterpret_cast<const h2v*>(&A[r]);
            #pragma unroll
            for (int c = 0; c < 4; ++c) {
                const h2v* bp = reinterpret_cast<const h2v*>(&Bv[c]);
                h2v t0 = ap[0] + bp[0];            // v_pk_add_f16
                h2v t1 = ap[1] + bp[1];
                h2v t2 = ap[2] + bp[2];
                h2v t3 = ap[3] + bp[3];
                accP[r][c] = hfma2(habs2(t0), wp[0], accP[r][c]);  // v_pk_fma_f16
                accP[r][c] = hfma2(habs2(t1), wp[1], accP[r][c]);
                accQ[r][c] = hfma2(habs2(t2), wp[2], accQ[r][c]);
                accQ[r][c] = hfma2(habs2(t3), wp[3], accQ[r][c]);
            }
        }
    }

    // Combine d-halves through LDS (A tile dead -> reuse as f32x4 buffer).
    __syncthreads();
    if (g == 1) {
        #pragma unroll
        for (int r = 0; r < 4; ++r) {
            float4 p;
            p.x = ((float)accP[r][0].x + (float)accP[r][0].y)
                + ((float)accQ[r][0].x + (float)accQ[r][0].y);
            p.y = ((float)accP[r][1].x + (float)accP[r][1].y)
                + ((float)accQ[r][1].x + (float)accQ[r][1].y);
            p.z = ((float)accP[r][2].x + (float)accP[r][2].y)
                + ((float)accQ[r][2].x + (float)accQ[r][2].y);
            p.w = ((float)accP[r][3].x + (float)accP[r][3].y)
                + ((float)accQ[r][3].x + (float)accQ[r][3].y);
            sTileI[t8 * 4 + (r ^ (t8 & 3))] = p;
        }
    }
    __syncthreads();
    if (g == 0) {
        #pragma unroll
        for (int r = 0; r < 4; ++r) {
            const float4 p = sTileI[t8 * 4 + (r ^ (t8 & 3))];
            const float sv = sSi[ri + r];
            float4 o;
            o.x = ((float)accP[r][0].x + (float)accP[r][0].y)
                + ((float)accQ[r][0].x + (float)accQ[r][0].y) + p.x + sv + sSj[cj + 0];
            o.y = ((float)accP[r][1].x + (float)accP[r][1].y)
                + ((float)accQ[r][1].x + (float)accQ[r][1].y) + p.y + sv + sSj[cj + 1];
            o.z = ((float)accP[r][2].x + (float)accP[r][2].y)
                + ((float)accQ[r][2].x + (float)accQ[r][2].y) + p.z + sv + sSj[cj + 2];
            o.w = ((float)accP[r][3].x + (float)accP[r][3].y)
                + ((float)accQ[r][3].x + (float)accQ[r][3].y) + p.w + sv + sSj[cj + 3];
            size_t base = (size_t)b * SDIM * SDIM
                        + (size_t)(i0 + ri + r) * SDIM + j0 + cj;
            *reinterpret_cast<float4*>(out + base) = o;
        }
    }
}

extern "C" void kernel_launch(void* const* d_in, const int* in_sizes, int n_in,
                              void* d_out, int out_size, void* d_ws, size_t ws_size,
                              hipStream_t stream) {
    const float* x  = (const float*)d_in[0];
    const float* W1 = (const float*)d_in[1];
    const float* b1 = (const float*)d_in[2];
    const float* W2 = (const float*)d_in[3];
    const float* b2 = (const float*)d_in[4];
    float* out = (float*)d_out;

    char* ws = (char*)d_ws;
    ushort* hi16  = (ushort*)ws;                                   // B*S*D f16
    ushort* hjb16 = hi16 + (size_t)BB * SDIM * DDIM;               // B*S*D f16
    float*  si2   = (float*)(hjb16 + (size_t)BB * SDIM * DDIM);    // B*S f32
    float*  sj2   = si2 + (size_t)BB * SDIM;                       // B*S f32

    proj_kernel<<<BB * SDIM / K1_ROWS, 256, 0, stream>>>(x, W1, b1, W2, b2, hi16, hjb16, si2, sj2);
    edge_kernel<<<dim3(SDIM / 64, SDIM / 64, BB), 512, 0, stream>>>(hi16, hjb16, si2, sj2, W2, out);
}